// Round 7
// baseline (212.550 us; speedup 1.0000x reference)
//
#include <hip/hip_runtime.h>

typedef float f32x4 __attribute__((ext_vector_type(4)));
typedef __bf16 bf16x8 __attribute__((ext_vector_type(8)));

typedef __attribute__((address_space(3))) unsigned char lds_u8;
typedef __attribute__((address_space(1))) const unsigned char g_u8c;

__device__ __forceinline__ unsigned short f2bf(float f) {
  unsigned int u = __float_as_uint(f);
  u += 0x7FFFu + ((u >> 16) & 1u);   // round-to-nearest-even
  return (unsigned short)(u >> 16);
}
__device__ __forceinline__ unsigned int pk2(float a, float b) {
  return (unsigned int)f2bf(a) | ((unsigned int)f2bf(b) << 16);
}
__device__ __forceinline__ void gload16(const void* g, void* l) {
  __builtin_amdgcn_global_load_lds((g_u8c*)g, (lds_u8*)l, 16, 0, 0);
}

// ---- Kernel 0: weights -> bf16, fragment-contiguous layout + bias sum ----
// b-fragment for (kt,ct) is 1KB contiguous: wt[(kt*8+ct)*512 + lane*8 + j],
// lane=lg*16+l15 maps to (n=ct*16+l15, k=kt*32+lg*8+j).
__global__ void k_prep(const float* __restrict__ Ws, const float* __restrict__ Wn,
                       const float* __restrict__ bs, const float* __restrict__ bn,
                       unsigned short* __restrict__ wt, float* __restrict__ bias) {
  int idx = blockIdx.x * 256 + threadIdx.x;   // 0..32767
  int n = idx >> 8, k = idx & 255;
  float v = (k < 128) ? Ws[k * 128 + n] : Wn[(k - 128) * 128 + n];
  int ct = n >> 4, l15 = n & 15, kt = k >> 5, lg = (k >> 3) & 3, j = k & 7;
  wt[(((kt << 3) | ct) << 9) + (((lg << 4) | l15) << 3) + j] = f2bf(v);
  if (idx < 128) bias[idx] = bs[idx] + bn[idx];
}

// ---- Fused: 4 independent waves/WG, 8KB LDS/wave (src only), zero barriers ----
__global__ __launch_bounds__(256, 4) void k_fused(
    const float* __restrict__ src, const float* __restrict__ dstf,
    const int* __restrict__ dst, const unsigned short* __restrict__ wt,
    const float* __restrict__ bias, float* __restrict__ out, int E)
{
  // per-wave slab: 16 src rows f32, 512B each, XOR-swizzled; after the scan
  // consumes row r, bytes [0,256) of that row hold the bf16 h row.
  __shared__ __align__(16) unsigned char slab[4][8192];
  const int lane = threadIdx.x & 63, wid = threadIdx.x >> 6;
  const int l15 = lane & 15, lg = lane >> 4;

  // bijective XCD swizzle (m204)
  const int nwg = gridDim.x, bid = blockIdx.x;
  const int q = nwg >> 3, r = nwg & 7;
  const int xcd = bid & 7, ix = bid >> 3;
  const int swb = (xcd < r ? xcd * (q + 1) : r * (q + 1) + (xcd - r) * q) + ix;

  const long e0 = ((long)swb * 4 + wid) * 16;
  if (e0 >= E) return;                         // no barriers anywhere -> safe
  const long emax = (long)E - 1;
  unsigned char* ssrc = slab[wid];

  // ---- dst index loads first (feed ballot + reset mask) ----
  long rc = e0 + l15; if (rc > emax) rc = emax;
  int dcur = dst[rc];
  long rp = rc - 1; if (rp < 0) rp = 0;
  int dprev = dst[rp];
  long back = e0 - 1 - lane;
  long backc = back < 0 ? 0 : back;
  int bd = dst[backc];

  // ---- async stage: 16 src rows (1KB per issue, inverse-swizzled source) ----
  #pragma unroll
  for (int i = 0; i < 8; ++i) {
    int r2 = i * 2 + (lane >> 5);
    long gr = e0 + r2; if (gr > emax) gr = emax;
    int colb = ((lane & 31) << 4) ^ ((r2 & 7) << 5);
    gload16((const char*)src + gr * 512 + colb, ssrc + i * 1024);
  }

  // ---- per-row bucket-start mask (bit r: row e0+r starts a new bucket) ----
  unsigned mask16 = (unsigned)(__ballot((rc > 0) && (dcur != dprev)) & 0xFFFFull);

  // ---- bucket start of row e0 via ballot over back rows ----
  int d0 = __shfl(dcur, 0);
  unsigned long long m = __ballot((back >= 0) && (bd == d0));
  unsigned long long nm = ~m;
  int L = (nm == 0ull) ? 64 : __builtin_ctzll(nm);
  long s = e0 - L;
  while (s > 0 && dst[s - 1] == d0) --s;       // bucket >64 deep: ~never

  // ---- batched partial-bucket base sum (independent loads per batch) ----
  float ax = 0.f, ay = 0.f;
  long e = s;
  while (e < e0) {
    int nb = (int)(e0 - e); if (nb > 8) nb = 8;
    float2 t[8];
    #pragma unroll
    for (int j = 0; j < 8; ++j)
      if (j < nb) t[j] = *(const float2*)(src + (e + j) * 128 + lane * 2);
    #pragma unroll
    for (int j = 0; j < 8; ++j)
      if (j < nb) { ax += t[j].x; ay += t[j].y; }
    e += nb;
  }
  int pos = (int)(e0 - s);

  // src rows staged (also drains base-sum/index loads)
  asm volatile("s_waitcnt vmcnt(0)" ::: "memory");

  // ---- cummean scan: read src row r from LDS, write h row r (bf16) over it ----
  #pragma unroll
  for (int rr = 0; rr < 16; ++rr) {
    if (mask16 & (1u << rr)) { ax = 0.f; ay = 0.f; pos = 0; }
    float2 v = *(const float2*)(ssrc + rr * 512 + ((lane * 8) ^ ((rr & 7) << 5)));
    ax += v.x; ay += v.y;
    float inv = __builtin_amdgcn_rcpf((float)(pos + 1));
    *(unsigned int*)(ssrc + rr * 512 + ((lane * 4) ^ ((rr & 7) << 4))) = pk2(ax * inv, ay * inv);
    ++pos;
  }

  asm volatile("s_waitcnt lgkmcnt(0)" ::: "memory");   // h writes landed

  // ---- MFMA: 16 rows x 128 cols, K=256 ----
  // dstf fragments: 8 independent loads issued together (one round-trip)
  long arow = e0 + l15; if (arow > emax) arow = emax;
  const float* ap = dstf + arow * 128 + lg * 8;
  float4 af[8];
  #pragma unroll
  for (int kt = 0; kt < 4; ++kt) {
    af[kt * 2]     = *(const float4*)(ap + kt * 32);
    af[kt * 2 + 1] = *(const float4*)(ap + kt * 32 + 4);
  }

  f32x4 acc[8];
  #pragma unroll
  for (int ct = 0; ct < 8; ++ct) acc[ct] = (f32x4){0.f, 0.f, 0.f, 0.f};
  float bcol[8];
  #pragma unroll
  for (int ct = 0; ct < 8; ++ct) bcol[ct] = bias[ct * 16 + l15];

  #pragma unroll
  for (int kt = 0; kt < 8; ++kt) {
    bf16x8 a;
    if (kt < 4) {                              // dst_feat (prefetched f32 -> bf16)
      float4 x = af[kt * 2], y = af[kt * 2 + 1];
      union { unsigned int u[4]; bf16x8 v; } cv;
      cv.u[0] = pk2(x.x, x.y); cv.u[1] = pk2(x.z, x.w);
      cv.u[2] = pk2(y.x, y.y); cv.u[3] = pk2(y.z, y.w);
      a = cv.v;
    } else {                                   // h bf16 from LDS (overlaid in ssrc)
      a = *(const bf16x8*)(ssrc + l15 * 512 + ((((kt - 4) * 64) + lg * 16) ^ ((l15 & 7) << 4)));
    }
    bf16x8 b[8];
    #pragma unroll
    for (int ct = 0; ct < 8; ++ct)             // 1KB coalesced fragment (L2-hot)
      b[ct] = *(const bf16x8*)(wt + (((kt << 3) | ct) << 9) + (lane << 3));
    #pragma unroll
    for (int ct = 0; ct < 8; ++ct)
      acc[ct] = __builtin_amdgcn_mfma_f32_16x16x32_bf16(a, b[ct], acc[ct], 0, 0, 0);
  }

  // ---- epilogue: D layout col=lane&15, row=(lane>>4)*4+i ----
  #pragma unroll
  for (int i = 0; i < 4; ++i) {
    long row = e0 + lg * 4 + i;
    if (row < E) {
      float* op = out + row * 128 + l15;
      #pragma unroll
      for (int ct = 0; ct < 8; ++ct) op[ct * 16] = acc[ct][i] + bcol[ct];
    }
  }
}

extern "C" void kernel_launch(void* const* d_in, const int* in_sizes, int n_in,
                              void* d_out, int out_size, void* d_ws, size_t ws_size,
                              hipStream_t stream) {
  const float* src_feat = (const float*)d_in[0];
  const float* dst_feat = (const float*)d_in[1];
  const int*   dst      = (const int*)d_in[2];
  const float* W_self   = (const float*)d_in[3];
  const float* b_self   = (const float*)d_in[4];
  const float* W_neigh  = (const float*)d_in[5];
  const float* b_neigh  = (const float*)d_in[6];
  float* out = (float*)d_out;
  const int E = in_sizes[2];

  unsigned short* wt   = (unsigned short*)d_ws;           // 64KB repacked weights
  float*          bias = (float*)((char*)d_ws + 65536);   // 512B

  k_prep<<<128, 256, 0, stream>>>(W_self, W_neigh, b_self, b_neigh, wt, bias);

  int blocks = (E + 63) / 64;   // 4 waves/WG x 16 rows/wave
  k_fused<<<blocks, 256, 0, stream>>>(src_feat, dst_feat, dst, wt, bias, out, E);
}

// Round 8
// 175.715 us; speedup vs baseline: 1.2096x; 1.2096x over previous
//
#include <hip/hip_runtime.h>

typedef float f32x4 __attribute__((ext_vector_type(4)));
typedef __bf16 bf16x8 __attribute__((ext_vector_type(8)));

typedef __attribute__((address_space(3))) unsigned char lds_u8;
typedef __attribute__((address_space(1))) const unsigned char g_u8c;

__device__ __forceinline__ unsigned short f2bf(float f) {
  unsigned int u = __float_as_uint(f);
  u += 0x7FFFu + ((u >> 16) & 1u);   // round-to-nearest-even
  return (unsigned short)(u >> 16);
}
__device__ __forceinline__ unsigned int pk2(float a, float b) {
  return (unsigned int)f2bf(a) | ((unsigned int)f2bf(b) << 16);
}
__device__ __forceinline__ void gload16(const void* g, void* l) {
  __builtin_amdgcn_global_load_lds((g_u8c*)g, (lds_u8*)l, 16, 0, 0);
}

#define SPAN 256   // rows per workgroup (8 tiles x 32)

// ---- k_prep: weights -> bf16 in per-(wave,frag) 1KB blocks + bias sum ----
// wt2[((w*16 + kt*2 + c2)*64 + lg*16 + l15)*8 + j] = W^T[n][k],
// n = w*32 + c2*16 + l15, k = kt*32 + lg*8 + j.  (128 KB total)
__global__ void k_prep(const float* __restrict__ Ws, const float* __restrict__ Wn,
                       const float* __restrict__ bs, const float* __restrict__ bn,
                       unsigned short* __restrict__ wt2, float* __restrict__ bias) {
  int idx = blockIdx.x * 256 + threadIdx.x;   // 0..32767
  int n = idx >> 8, k = idx & 255;
  float v = (k < 128) ? Ws[k * 128 + n] : Wn[(k - 128) * 128 + n];
  int w = n >> 5, c2 = (n >> 4) & 1, l15 = n & 15;
  int kt = k >> 5, lg = (k >> 3) & 3, j = k & 7;
  wt2[(((w * 16 + kt * 2 + c2) * 64) + lg * 16 + l15) * 8 + j] = f2bf(v);
  if (idx < 128) bias[idx] = bs[idx] + bn[idx];
}

// ---- Fused persistent kernel: WG owns 256 rows; wave owns 32 output cols
// with its B-slice resident in 64 VGPRs for the whole span. ----
__global__ __launch_bounds__(256) void k_fused(
    const float* __restrict__ src, const float* __restrict__ dstf,
    const int* __restrict__ dst, const unsigned short* __restrict__ wt2,
    const float* __restrict__ bias, float* __restrict__ out, int E, int nwg)
{
  __shared__ __align__(16) unsigned char sbuf[32 * 512];   // src f32, swz ^((r&7)<<5)
  __shared__ __align__(16) unsigned char dbuf[32 * 512];   // dstf f32, same swz
  __shared__ __align__(16) unsigned char hbuf[32 * 256];   // h bf16, swz ^((r&7)<<4)

  const int lane = threadIdx.x & 63, wid = threadIdx.x >> 6;
  const int l15 = lane & 15, lg = lane >> 4, l31 = lane & 31;
  const long emax = (long)E - 1;

  // bijective XCD swizzle (m204)
  const int bid = blockIdx.x;
  const int q = nwg >> 3, r = nwg & 7;
  const int xcd = bid & 7, ix = bid >> 3;
  const int swb = (xcd < r ? xcd * (q + 1) : r * (q + 1) + (xcd - r) * q) + ix;

  const long W0 = (long)swb * SPAN;
  const long Wend = (W0 + SPAN < (long)E) ? W0 + SPAN : (long)E;
  const int nt = (int)((Wend - W0 + 31) >> 5);   // WG-uniform tile count

  // ---- persistent B slice: cols [wid*32, wid*32+32), 16 KB -> 64 VGPRs ----
  bf16x8 b[16];
  #pragma unroll
  for (int f = 0; f < 16; ++f)
    b[f] = *(const bf16x8*)(wt2 + ((wid * 16 + f) * 64 + lane) * 8);
  const float bc0 = bias[wid * 32 + l15];
  const float bc1 = bias[wid * 32 + 16 + l15];

  const int mycol = wid * 32 + l31;   // scan column owned by this lane

  // ---- prologue (once per 256 rows): bucket start + base-sum carry ----
  int d0 = dst[W0];
  long back = W0 - 1 - lane;
  long backc = back < 0 ? 0 : back;
  int bd = dst[backc];
  unsigned long long m = __ballot((back >= 0) && (bd == d0));
  unsigned long long nm = ~m;
  int L = (nm == 0ull) ? 64 : __builtin_ctzll(nm);
  long s = W0 - L;
  while (s > 0 && dst[s - 1] == d0) --s;        // bucket >64 deep: ~never
  float ax = 0.f;
  if (lane < 32) {
    long e = s;
    while (e < W0) {
      int nb = (int)(W0 - e); if (nb > 8) nb = 8;
      float tv[8];
      #pragma unroll
      for (int j2 = 0; j2 < 8; ++j2)
        if (j2 < nb) tv[j2] = src[(e + j2) * 128 + mycol];
      #pragma unroll
      for (int j2 = 0; j2 < 8; ++j2)
        if (j2 < nb) ax += tv[j2];
      e += nb;
    }
  }
  int pos = (int)(W0 - s);

  // ---- stage tile 0 (src + dstf; linear LDS dest, inverse-swizzled source) ----
  #pragma unroll
  for (int qd = 0; qd < 4; ++qd) {
    int i = wid * 4 + qd;
    int r2 = i * 2 + (lane >> 5);
    long gr = W0 + r2; if (gr > emax) gr = emax;
    int colb = (l31 << 4) ^ ((r2 & 7) << 5);
    gload16((const char*)src + gr * 512 + colb, sbuf + i * 1024);
    gload16((const char*)dstf + gr * 512 + colb, dbuf + i * 1024);
  }

  for (int t = 0; t < nt; ++t) {
    const long tb = W0 + (long)t * 32;

    // reset-mask loads (prefetched; drained by barrier1's implicit vmcnt)
    long rc = tb + l31; if (rc > emax) rc = emax;
    int dcur = dst[rc];
    long rp = rc - 1; if (rp < 0) rp = 0;
    int dprev = dst[rp];

    __syncthreads();   // barrier1: stage(t) landed

    unsigned mask = (unsigned)__ballot((lane < 32) && (rc > 0) && (dcur != dprev));

    // ---- segmented cummean scan: 1 col/lane, rows serial, carry in regs ----
    if (lane < 32) {
      #pragma unroll
      for (int rr = 0; rr < 32; ++rr) {
        if ((mask >> rr) & 1u) { ax = 0.f; pos = 0; }
        float v = *(const float*)(sbuf + rr * 512 + ((mycol * 4) ^ ((rr & 7) << 5)));
        ax += v;
        float mean = ax * __builtin_amdgcn_rcpf((float)(pos + 1));
        *(unsigned short*)(hbuf + rr * 256 + ((mycol * 2) ^ ((rr & 7) << 4))) = f2bf(mean);
        ++pos;
      }
    }

    __syncthreads();   // barrier2: h ready, sbuf fully consumed

    // ---- dstf A-fragments -> regs (shared rows, bf16) ----
    bf16x8 abf[2][4];
    #pragma unroll
    for (int rt = 0; rt < 2; ++rt) {
      int row = rt * 16 + l15;
      #pragma unroll
      for (int kt = 0; kt < 4; ++kt) {
        const unsigned char* p = dbuf + row * 512 + ((kt * 128 + lg * 32) ^ ((row & 7) << 5));
        float4 x = *(const float4*)p;
        float4 y = *(const float4*)(p + 16);
        union { unsigned int u[4]; bf16x8 v; } cv;
        cv.u[0] = pk2(x.x, x.y); cv.u[1] = pk2(x.z, x.w);
        cv.u[2] = pk2(y.x, y.y); cv.u[3] = pk2(y.z, y.w);
        abf[rt][kt] = cv.v;
      }
    }

    __syncthreads();   // barrier3: dbuf consumed by all waves

    if (t + 1 < nt) {  // stage(t+1): flies under MFMA + stores
      const long nb2 = tb + 32;
      #pragma unroll
      for (int qd = 0; qd < 4; ++qd) {
        int i = wid * 4 + qd;
        int r2 = i * 2 + (lane >> 5);
        long gr = nb2 + r2; if (gr > emax) gr = emax;
        int colb = (l31 << 4) ^ ((r2 & 7) << 5);
        gload16((const char*)src + gr * 512 + colb, sbuf + i * 1024);
        gload16((const char*)dstf + gr * 512 + colb, dbuf + i * 1024);
      }
    }

    // ---- MFMA: 32 rows x 32 cols, K=256, B resident in regs ----
    #pragma unroll
    for (int rt = 0; rt < 2; ++rt) {
      int row = rt * 16 + l15;
      f32x4 a0 = {0.f, 0.f, 0.f, 0.f}, a1 = {0.f, 0.f, 0.f, 0.f};
      #pragma unroll
      for (int kt = 0; kt < 8; ++kt) {
        bf16x8 a;
        if (kt < 4) {
          a = abf[rt][kt];
        } else {       // h bf16 from LDS (stable until next barrier1)
          a = *(const bf16x8*)(hbuf + row * 256 + ((((kt - 4) * 64) + lg * 16) ^ ((row & 7) << 4)));
        }
        a0 = __builtin_amdgcn_mfma_f32_16x16x32_bf16(a, b[kt * 2 + 0], a0, 0, 0, 0);
        a1 = __builtin_amdgcn_mfma_f32_16x16x32_bf16(a, b[kt * 2 + 1], a1, 0, 0, 0);
      }
      // D layout: col=lane&15, row=(lane>>4)*4+i
      #pragma unroll
      for (int i = 0; i < 4; ++i) {
        long row2 = tb + rt * 16 + lg * 4 + i;
        if (row2 < E) {
          float* op = out + row2 * 128 + wid * 32 + l15;
          op[0]  = a0[i] + bc0;
          op[16] = a1[i] + bc1;
        }
      }
    }
  }
}

extern "C" void kernel_launch(void* const* d_in, const int* in_sizes, int n_in,
                              void* d_out, int out_size, void* d_ws, size_t ws_size,
                              hipStream_t stream) {
  const float* src_feat = (const float*)d_in[0];
  const float* dst_feat = (const float*)d_in[1];
  const int*   dst      = (const int*)d_in[2];
  const float* W_self   = (const float*)d_in[3];
  const float* b_self   = (const float*)d_in[4];
  const float* W_neigh  = (const float*)d_in[5];
  const float* b_neigh  = (const float*)d_in[6];
  float* out = (float*)d_out;
  const int E = in_sizes[2];

  unsigned short* wt2  = (unsigned short*)d_ws;            // 128 KB repacked W
  float*          bias = (float*)((char*)d_ws + 131072);   // 512 B

  k_prep<<<128, 256, 0, stream>>>(W_self, W_neigh, b_self, b_neigh, wt2, bias);

  int nwg = (E + SPAN - 1) / SPAN;
  k_fused<<<nwg, 256, 0, stream>>>(src_feat, dst_feat, dst, wt2, bias, out, E, nwg);
}